// Round 10
// baseline (150.568 us; speedup 1.0000x reference)
//
#include <hip/hip_runtime.h>

#define NEG_SLOPE 0.01f
#define LOG2E 1.4426950408889634f

constexpr int N = 8192;
constexpr int D = 64;
constexpr int RB = 32;   // output rows per block
constexpr int NW = 8;    // waves per block (512 threads)

typedef __bf16 bf16x8 __attribute__((ext_vector_type(8)));
typedef float f32x4 __attribute__((ext_vector_type(4)));

// ============ single plain-dispatch kernel (no grid sync needed) ============
// Every cross-block dependency is recomputed block-locally:
//  - s1 for ALL 8192 j (full GEMV sweep, x L2-resident) -> LDS (32 KB)
//  - exact global max(s1) from the local copy
//  - B-fragments built on the fly: frag-ordered coalesced f32 loads + cvt
// Then the proven R8 flash loop: P-frag in regs, 8 MFMA + 2 Z-MFMA per window.
__global__ __launch_bounds__(512, 2) void gat_one(
    const float* __restrict__ x, const float* __restrict__ W_,
    const float* __restrict__ b, const float* __restrict__ a,
    float* __restrict__ out) {
  __shared__ float w1s[D], w2s[D], cs[2];
  __shared__ float s1All[N];          // 32 KB
  __shared__ float s2loc[RB];
  __shared__ float wmax[NW];
  __shared__ float accT[NW][RB][64];  // 64 KB
  __shared__ float zt[NW][RB];

  const int t = threadIdx.x;
  const int bid = blockIdx.x;
  const int lane = t & 63;
  const int w = t >> 6;

  // ---- Phase 0: w1/w2 = log2e * W^T a1/a2 (W 16KB, L2-hot) ----
  if (t < 128) {
    const int sel = t >> 6, d = t & 63;
    const float* av = a + sel * D;
    float acc = 0.f;
#pragma unroll
    for (int k = 0; k < D; ++k) acc += W_[k * D + d] * av[k];
    (sel ? w2s : w1s)[d] = acc * LOG2E;
  }
  if (t == 128 || t == 129) {
    const int sel = t - 128;
    float acc = 0.f;
    for (int d = 0; d < D; ++d) acc += b[d] * a[sel * D + d];
    cs[sel] = acc * LOG2E;
  }
  __syncthreads();

  // ---- Phase 1: full s1 sweep (all N rows); s2 for own 32 rows ----
  {
    const int seg = t & 7;      // 8 lanes per row
    const int rloc = t >> 3;    // 0..63 rows per iteration
    float w1r[8], w2r[8];
#pragma unroll
    for (int k = 0; k < 8; ++k) { w1r[k] = w1s[seg * 8 + k]; w2r[k] = w2s[seg * 8 + k]; }
    const float c1 = cs[0], c2 = cs[1];
#pragma unroll 4
    for (int it = 0; it < N / 64; ++it) {
      const int gi = it * 64 + rloc;
      const float4 xa = *(const float4*)(x + (size_t)gi * D + seg * 8);
      const float4 xb = *(const float4*)(x + (size_t)gi * D + seg * 8 + 4);
      float p1 = xa.x * w1r[0] + xa.y * w1r[1] + xa.z * w1r[2] + xa.w * w1r[3] +
                 xb.x * w1r[4] + xb.y * w1r[5] + xb.z * w1r[6] + xb.w * w1r[7];
      float p2 = xa.x * w2r[0] + xa.y * w2r[1] + xa.z * w2r[2] + xa.w * w2r[3] +
                 xb.x * w2r[4] + xb.y * w2r[5] + xb.z * w2r[6] + xb.w * w2r[7];
#pragma unroll
      for (int off = 1; off < 8; off <<= 1) {
        p1 += __shfl_xor(p1, off, 64);
        p2 += __shfl_xor(p2, off, 64);
      }
      if (seg == 0) {
        s1All[gi] = p1 + c1;
        const int rown = gi - bid * RB;
        if ((unsigned)rown < (unsigned)RB) s2loc[rown] = p2 + c2;
      }
    }
  }
  __syncthreads();

  // ---- Phase 1b: exact global max(s1) from the local copy ----
  float gm;
  {
    float mv = -1e30f;
#pragma unroll
    for (int k = 0; k < N / 512; ++k) mv = fmaxf(mv, s1All[k * 512 + t]);
#pragma unroll
    for (int off = 32; off; off >>= 1) mv = fmaxf(mv, __shfl_xor(mv, off, 64));
    if (lane == 0) wmax[w] = mv;
    __syncthreads();
    gm = wmax[0];
#pragma unroll
    for (int k = 1; k < NW; ++k) gm = fmaxf(gm, wmax[k]);
  }

  // ---- Phase 2: MFMA flash loop (waves split j-windows mod 8) ----
  const int arow = lane & 15;
  const int grp = lane >> 4;
  const float s2v0 = s2loc[arow];
  const float s2v1 = s2loc[16 + arow];
  const float tm0 = s2v0 + gm, tm1 = s2v1 + gm;
  const float mneg0 = -fmaxf(tm0, NEG_SLOPE * tm0);  // -m_i (leaky monotone)
  const float mneg1 = -fmaxf(tm1, NEG_SLOPE * tm1);

  f32x4 a00 = {0.f, 0.f, 0.f, 0.f}, a01 = a00, a02 = a00, a03 = a00;
  f32x4 a10 = a00, a11 = a00, a12 = a00, a13 = a00;
  f32x4 az0 = a00, az1 = a00;
  bf16x8 ones;
#pragma unroll
  for (int q = 0; q < 8; ++q) ones[q] = (__bf16)1.0f;

  // frag-ordered f32 window loads: lane base = row (c*32 + grp*8), col arow;
  // offsets q*64 + dt*16 floats -> lanes 0-15 read 16 consecutive cols (64B segs)
  float xc[32], xn[32];
  float4 sa, sb, na, nb;
  {
    const float* bp = x + (size_t)w * 2048 + grp * 512 + arow;
#pragma unroll
    for (int q = 0; q < 8; ++q)
#pragma unroll
      for (int dt = 0; dt < 4; ++dt) xc[q * 4 + dt] = bp[q * 64 + dt * 16];
    const float* sp = &s1All[w * 32 + grp * 8];
    sa = *(const float4*)sp;
    sb = *(const float4*)(sp + 4);
  }

  constexpr int ITERS = N / 32 / NW;  // 32
  int c = w;
  for (int i = 0; i < ITERS; ++i) {
    const int cn = (i == ITERS - 1) ? c : c + NW;  // last iter: dummy reload
    {
      const float* bp = x + (size_t)cn * 2048 + grp * 512 + arow;
#pragma unroll
      for (int q = 0; q < 8; ++q)
#pragma unroll
        for (int dt = 0; dt < 4; ++dt) xn[q * 4 + dt] = bp[q * 64 + dt * 16];
      const float* sp = &s1All[cn * 32 + grp * 8];
      na = *(const float4*)sp;
      nb = *(const float4*)(sp + 4);
    }

    // B-frags from current window (cvt f32->bf16)
    bf16x8 xb0, xb1, xb2, xb3;
#pragma unroll
    for (int q = 0; q < 8; ++q) {
      xb0[q] = (__bf16)xc[q * 4 + 0];
      xb1[q] = (__bf16)xc[q * 4 + 1];
      xb2[q] = (__bf16)xc[q * 4 + 2];
      xb3[q] = (__bf16)xc[q * 4 + 3];
    }

    // P-frags in log2 domain: p = 2^(max(t,0.01t) + mneg)
    bf16x8 pa0, pa1;
    {
      const float* sv = &sa.x;
#pragma unroll
      for (int q = 0; q < 4; ++q) {
        const float t0 = s2v0 + sv[q];
        pa0[q] = (__bf16)exp2f(fmaxf(t0, NEG_SLOPE * t0) + mneg0);
        const float t1 = s2v1 + sv[q];
        pa1[q] = (__bf16)exp2f(fmaxf(t1, NEG_SLOPE * t1) + mneg1);
      }
      const float* sw = &sb.x;
#pragma unroll
      for (int q = 0; q < 4; ++q) {
        const float t0 = s2v0 + sw[q];
        pa0[4 + q] = (__bf16)exp2f(fmaxf(t0, NEG_SLOPE * t0) + mneg0);
        const float t1 = s2v1 + sw[q];
        pa1[4 + q] = (__bf16)exp2f(fmaxf(t1, NEG_SLOPE * t1) + mneg1);
      }
    }

    a00 = __builtin_amdgcn_mfma_f32_16x16x32_bf16(pa0, xb0, a00, 0, 0, 0);
    a01 = __builtin_amdgcn_mfma_f32_16x16x32_bf16(pa0, xb1, a01, 0, 0, 0);
    a02 = __builtin_amdgcn_mfma_f32_16x16x32_bf16(pa0, xb2, a02, 0, 0, 0);
    a03 = __builtin_amdgcn_mfma_f32_16x16x32_bf16(pa0, xb3, a03, 0, 0, 0);
    az0 = __builtin_amdgcn_mfma_f32_16x16x32_bf16(pa0, ones, az0, 0, 0, 0);
    a10 = __builtin_amdgcn_mfma_f32_16x16x32_bf16(pa1, xb0, a10, 0, 0, 0);
    a11 = __builtin_amdgcn_mfma_f32_16x16x32_bf16(pa1, xb1, a11, 0, 0, 0);
    a12 = __builtin_amdgcn_mfma_f32_16x16x32_bf16(pa1, xb2, a12, 0, 0, 0);
    a13 = __builtin_amdgcn_mfma_f32_16x16x32_bf16(pa1, xb3, a13, 0, 0, 0);
    az1 = __builtin_amdgcn_mfma_f32_16x16x32_bf16(pa1, ones, az1, 0, 0, 0);

#pragma unroll
    for (int q = 0; q < 32; ++q) xc[q] = xn[q];
    sa = na; sb = nb;
    c += NW;
  }

  // ---- epilogue (identical to R8): Z rows from az; cross-wave combine ----
  if (arow == 0) {
#pragma unroll
    for (int reg = 0; reg < 4; ++reg) {
      zt[w][grp * 4 + reg] = az0[reg];
      zt[w][16 + grp * 4 + reg] = az1[reg];
    }
  }
#pragma unroll
  for (int reg = 0; reg < 4; ++reg) {
    accT[w][grp * 4 + reg][0 * 16 + arow] = a00[reg];
    accT[w][grp * 4 + reg][1 * 16 + arow] = a01[reg];
    accT[w][grp * 4 + reg][2 * 16 + arow] = a02[reg];
    accT[w][grp * 4 + reg][3 * 16 + arow] = a03[reg];
    accT[w][16 + grp * 4 + reg][0 * 16 + arow] = a10[reg];
    accT[w][16 + grp * 4 + reg][1 * 16 + arow] = a11[reg];
    accT[w][16 + grp * 4 + reg][2 * 16 + arow] = a12[reg];
    accT[w][16 + grp * 4 + reg][3 * 16 + arow] = a13[reg];
  }
  __syncthreads();

#pragma unroll
  for (int k = 0; k < 4; ++k) {
    const int r = w * 4 + k;
    float s = 0.f, z = 0.f;
#pragma unroll
    for (int v = 0; v < NW; ++v) {
      s += accT[v][r][lane];
      z += zt[v][r];
    }
    out[(size_t)(bid * RB + r) * D + lane] = s / z;
  }
}

extern "C" void kernel_launch(void* const* d_in, const int* in_sizes, int n_in,
                              void* d_out, int out_size, void* d_ws, size_t ws_size,
                              hipStream_t stream) {
  const float* x = (const float*)d_in[0];   // 8192*64 f32
  const float* W = (const float*)d_in[1];   // 64*64
  const float* b = (const float*)d_in[2];   // 64
  const float* a = (const float*)d_in[3];   // 128
  float* out = (float*)d_out;

  gat_one<<<N / RB, 512, 0, stream>>>(x, W, b, a, out);
}

// Round 12
// 83.752 us; speedup vs baseline: 1.7978x; 1.7978x over previous
//
#include <hip/hip_runtime.h>

#define NEG_SLOPE 0.01f
#define LOG2E 1.4426950408889634f

constexpr int N = 8192;
constexpr int D = 64;
constexpr int PB = 32;   // rows per prep block == j-window span packed by that block
constexpr int RB = 32;   // rows per main block
constexpr int NW = 8;    // waves per main block (512 threads)

typedef __bf16 bf16x8 __attribute__((ext_vector_type(8)));
typedef float f32x4 __attribute__((ext_vector_type(4)));

#if __has_builtin(__builtin_amdgcn_exp2f)
#define EXP2(x) __builtin_amdgcn_exp2f(x)
#else
#define EXP2(x) exp2f(x)
#endif

// ---------------- K1: s1/s2 (log2e-scaled) + per-block max + bf16 pack ----------------
// (verbatim from R8 — passed twice)
__global__ __launch_bounds__(256) void gat_prep(
    const float* __restrict__ x, const float* __restrict__ W_,
    const float* __restrict__ b, const float* __restrict__ a,
    float* __restrict__ s1g, float* __restrict__ s2g,
    float* __restrict__ blockmax, bf16x8* __restrict__ xf) {
  __shared__ float w1s[D], w2s[D], cs[2];
  __shared__ float s1loc[PB];

  const int t = threadIdx.x;
  const int bid = blockIdx.x;

  if (t < 128) {
    const int sel = t >> 6, d = t & 63;
    const float* av = a + sel * D;
    float acc = 0.f;
#pragma unroll
    for (int k = 0; k < D; ++k) acc += W_[k * D + d] * av[k];
    (sel ? w2s : w1s)[d] = acc * LOG2E;
  }
  if (t == 128 || t == 129) {
    const int sel = t - 128;
    float acc = 0.f;
    for (int d = 0; d < D; ++d) acc += b[d] * a[sel * D + d];
    cs[sel] = acc * LOG2E;
  }
  __syncthreads();

  {
    const int r = t >> 3, seg = t & 7;
    const int gi = bid * PB + r;
    const float4 xa = *(const float4*)(x + (size_t)gi * D + seg * 8);
    const float4 xb = *(const float4*)(x + (size_t)gi * D + seg * 8 + 4);
    float p1 = xa.x * w1s[seg * 8 + 0] + xa.y * w1s[seg * 8 + 1] +
               xa.z * w1s[seg * 8 + 2] + xa.w * w1s[seg * 8 + 3] +
               xb.x * w1s[seg * 8 + 4] + xb.y * w1s[seg * 8 + 5] +
               xb.z * w1s[seg * 8 + 6] + xb.w * w1s[seg * 8 + 7];
    float p2 = xa.x * w2s[seg * 8 + 0] + xa.y * w2s[seg * 8 + 1] +
               xa.z * w2s[seg * 8 + 2] + xa.w * w2s[seg * 8 + 3] +
               xb.x * w2s[seg * 8 + 4] + xb.y * w2s[seg * 8 + 5] +
               xb.z * w2s[seg * 8 + 6] + xb.w * w2s[seg * 8 + 7];
#pragma unroll
    for (int off = 4; off; off >>= 1) {
      p1 += __shfl_xor(p1, off, 64);
      p2 += __shfl_xor(p2, off, 64);
    }
    if (seg == 0) {
      const float v1 = p1 + cs[0], v2 = p2 + cs[1];
      s1g[gi] = v1;
      s2g[gi] = v2;
      s1loc[r] = v1;
    }
  }

  {
    const int dt = t >> 6, fl = t & 63;
    const int jb = bid * PB + ((fl >> 4) << 3);
    const int col = dt * 16 + (fl & 15);
    bf16x8 f;
#pragma unroll
    for (int q = 0; q < 8; ++q) f[q] = (__bf16)x[(size_t)(jb + q) * D + col];
    xf[(bid << 8) | (dt << 6) | fl] = f;
  }
  __syncthreads();
  if (t == 0) {
    float m = s1loc[0];
#pragma unroll
    for (int r = 1; r < PB; ++r) m = fmaxf(m, s1loc[r]);
    blockmax[bid] = m;
  }
}

// ---------------- K2: MFMA flash aggregation, latency-optimized ----------------
// 256 blocks x 512 threads. s1 staged once to LDS; xf 2-deep register prefetch;
// folded P-math (add+fma+fmax+exp2 per p); Z via ones-MFMA; padded epilogue.
__global__ __launch_bounds__(512, 2) void gat_main(
    const bf16x8* __restrict__ xf, const float* __restrict__ s1g,
    const float* __restrict__ s2g, const float* __restrict__ blockmax,
    float* __restrict__ out) {
  __shared__ float s1s[N];             // 32 KB
  __shared__ float accT[NW][RB][65];   // 66.6 KB (padded stride: no bank conflict)
  __shared__ float zt[NW][RB];
  __shared__ float gms;

  const int t = threadIdx.x;
  const int lane = t & 63;
  const int w = t >> 6;
  const int arow = lane & 15;
  const int grp = lane >> 4;
  const int ibase = blockIdx.x * RB;

  // stage all s1 into LDS (coalesced float4)
#pragma unroll
  for (int k = 0; k < N / 4 / 512; ++k)
    ((float4*)s1s)[k * 512 + t] = ((const float4*)s1g)[k * 512 + t];

  // global max(s1) from blockmax[256]
  if (t < 64) {
    float v = fmaxf(fmaxf(blockmax[lane], blockmax[lane + 64]),
                    fmaxf(blockmax[lane + 128], blockmax[lane + 192]));
#pragma unroll
    for (int off = 32; off; off >>= 1) v = fmaxf(v, __shfl_xor(v, off, 64));
    if (lane == 0) gms = v;
  }
  __syncthreads();
  const float gm = gms;

  const float s2v0 = s2g[ibase + arow];
  const float s2v1 = s2g[ibase + 16 + arow];
  const float tm0 = s2v0 + gm, tm1 = s2v1 + gm;
  const float mneg0 = -fmaxf(tm0, NEG_SLOPE * tm0);  // -m_i (leaky monotone)
  const float mneg1 = -fmaxf(tm1, NEG_SLOPE * tm1);
  // folded constants: u = sv + A, v = fma(slope, sv, B), p = 2^max(u,v)
  const float A0 = s2v0 + mneg0, B0 = fmaf(NEG_SLOPE, s2v0, mneg0);
  const float A1 = s2v1 + mneg1, B1 = fmaf(NEG_SLOPE, s2v1, mneg1);

  f32x4 a00 = {0.f, 0.f, 0.f, 0.f}, a01 = a00, a02 = a00, a03 = a00;
  f32x4 a10 = a00, a11 = a00, a12 = a00, a13 = a00;
  f32x4 az0 = a00, az1 = a00;
  bf16x8 ones;
#pragma unroll
  for (int q = 0; q < 8; ++q) ones[q] = (__bf16)1.0f;

  // 2-deep prefetch buffers (named, static indices only)
  bf16x8 pA0, pA1, pA2, pA3, pB0, pB1, pB2, pB3;
  {
    const int fa = w << 8;
    pA0 = xf[fa + 0 * 64 + lane]; pA1 = xf[fa + 1 * 64 + lane];
    pA2 = xf[fa + 2 * 64 + lane]; pA3 = xf[fa + 3 * 64 + lane];
    const int fb = (w + NW) << 8;
    pB0 = xf[fb + 0 * 64 + lane]; pB1 = xf[fb + 1 * 64 + lane];
    pB2 = xf[fb + 2 * 64 + lane]; pB3 = xf[fb + 3 * 64 + lane];
  }

  auto process = [&](const bf16x8& x0, const bf16x8& x1, const bf16x8& x2,
                     const bf16x8& x3, int c) {
    const float4 sa = *(const float4*)&s1s[c * 32 + grp * 8];
    const float4 sb = *(const float4*)&s1s[c * 32 + grp * 8 + 4];
    bf16x8 pa0, pa1;
    const float* sv = &sa.x;
#pragma unroll
    for (int q = 0; q < 4; ++q) {
      const float s = sv[q];
      pa0[q] = (__bf16)EXP2(fmaxf(s + A0, fmaf(NEG_SLOPE, s, B0)));
      pa1[q] = (__bf16)EXP2(fmaxf(s + A1, fmaf(NEG_SLOPE, s, B1)));
    }
    const float* sw = &sb.x;
#pragma unroll
    for (int q = 0; q < 4; ++q) {
      const float s = sw[q];
      pa0[4 + q] = (__bf16)EXP2(fmaxf(s + A0, fmaf(NEG_SLOPE, s, B0)));
      pa1[4 + q] = (__bf16)EXP2(fmaxf(s + A1, fmaf(NEG_SLOPE, s, B1)));
    }
    a00 = __builtin_amdgcn_mfma_f32_16x16x32_bf16(pa0, x0, a00, 0, 0, 0);
    a01 = __builtin_amdgcn_mfma_f32_16x16x32_bf16(pa0, x1, a01, 0, 0, 0);
    a02 = __builtin_amdgcn_mfma_f32_16x16x32_bf16(pa0, x2, a02, 0, 0, 0);
    a03 = __builtin_amdgcn_mfma_f32_16x16x32_bf16(pa0, x3, a03, 0, 0, 0);
    az0 = __builtin_amdgcn_mfma_f32_16x16x32_bf16(pa0, ones, az0, 0, 0, 0);
    a10 = __builtin_amdgcn_mfma_f32_16x16x32_bf16(pa1, x0, a10, 0, 0, 0);
    a11 = __builtin_amdgcn_mfma_f32_16x16x32_bf16(pa1, x1, a11, 0, 0, 0);
    a12 = __builtin_amdgcn_mfma_f32_16x16x32_bf16(pa1, x2, a12, 0, 0, 0);
    a13 = __builtin_amdgcn_mfma_f32_16x16x32_bf16(pa1, x3, a13, 0, 0, 0);
    az1 = __builtin_amdgcn_mfma_f32_16x16x32_bf16(pa1, ones, az1, 0, 0, 0);
  };

  int c0 = w;
  constexpr int PAIRS = N / 32 / NW / 2;  // 16
  for (int i = 0; i < PAIRS; ++i) {
    // window c0 from A-buffer, then reload A for c0+16
    process(pA0, pA1, pA2, pA3, c0);
    {
      const int cn = (i == PAIRS - 1) ? c0 : c0 + 2 * NW;
      const int f = cn << 8;
      pA0 = xf[f + 0 * 64 + lane]; pA1 = xf[f + 1 * 64 + lane];
      pA2 = xf[f + 2 * 64 + lane]; pA3 = xf[f + 3 * 64 + lane];
    }
    // window c0+8 from B-buffer, then reload B for c0+24
    process(pB0, pB1, pB2, pB3, c0 + NW);
    {
      const int cn = (i == PAIRS - 1) ? c0 + NW : c0 + 3 * NW;
      const int f = cn << 8;
      pB0 = xf[f + 0 * 64 + lane]; pB1 = xf[f + 1 * 64 + lane];
      pB2 = xf[f + 2 * 64 + lane]; pB3 = xf[f + 3 * 64 + lane];
    }
    c0 += 2 * NW;
  }

  // ---- epilogue: Z rows from az; cross-wave combine through padded LDS ----
  if (arow == 0) {
#pragma unroll
    for (int reg = 0; reg < 4; ++reg) {
      zt[w][grp * 4 + reg] = az0[reg];
      zt[w][16 + grp * 4 + reg] = az1[reg];
    }
  }
#pragma unroll
  for (int reg = 0; reg < 4; ++reg) {
    accT[w][grp * 4 + reg][0 * 16 + arow] = a00[reg];
    accT[w][grp * 4 + reg][1 * 16 + arow] = a01[reg];
    accT[w][grp * 4 + reg][2 * 16 + arow] = a02[reg];
    accT[w][grp * 4 + reg][3 * 16 + arow] = a03[reg];
    accT[w][16 + grp * 4 + reg][0 * 16 + arow] = a10[reg];
    accT[w][16 + grp * 4 + reg][1 * 16 + arow] = a11[reg];
    accT[w][16 + grp * 4 + reg][2 * 16 + arow] = a12[reg];
    accT[w][16 + grp * 4 + reg][3 * 16 + arow] = a13[reg];
  }
  __syncthreads();

#pragma unroll
  for (int k = 0; k < 4; ++k) {
    const int r = w * 4 + k;
    float s = 0.f, z = 0.f;
#pragma unroll
    for (int v = 0; v < NW; ++v) {
      s += accT[v][r][lane];
      z += zt[v][r];
    }
    out[(size_t)(ibase + r) * D + lane] = s / z;
  }
}

extern "C" void kernel_launch(void* const* d_in, const int* in_sizes, int n_in,
                              void* d_out, int out_size, void* d_ws, size_t ws_size,
                              hipStream_t stream) {
  const float* x = (const float*)d_in[0];   // 8192*64 f32
  const float* W = (const float*)d_in[1];   // 64*64
  const float* b = (const float*)d_in[2];   // 64
  const float* a = (const float*)d_in[3];   // 128

  // ws: s1[8192] | s2[8192] | blockmax[256] | @1MB: xf (1MB bf16 frags)
  float* s1 = (float*)d_ws;
  float* s2 = s1 + N;
  float* blockmax = s2 + N;
  bf16x8* xf = (bf16x8*)((char*)d_ws + (1u << 20));
  float* out = (float*)d_out;

  gat_prep<<<N / PB, 256, 0, stream>>>(x, W, b, a, s1, s2, blockmax, xf);
  gat_main<<<N / RB, 512, 0, stream>>>(xf, s1, s2, blockmax, out);
}

// Round 13
// 83.287 us; speedup vs baseline: 1.8078x; 1.0056x over previous
//
#include <hip/hip_runtime.h>

#define NEG_SLOPE 0.01f
#define LOG2E 1.4426950408889634f

constexpr int N = 8192;
constexpr int D = 64;
constexpr int PB = 32;     // rows per prep block == j-window span packed by that block
constexpr int RB = 64;     // rows per main block (i-tile height)
constexpr int NW = 8;      // waves per main block (512 threads)
constexpr int NWIN_H = 128;  // j-windows per half (of 256 total)

typedef __bf16 bf16x8 __attribute__((ext_vector_type(8)));
typedef float f32x4 __attribute__((ext_vector_type(4)));

#if __has_builtin(__builtin_amdgcn_exp2f)
#define EXP2(x) __builtin_amdgcn_exp2f(x)
#else
#define EXP2(x) exp2f(x)
#endif

// ---------------- K1: s1/s2 (log2e-scaled) + per-block max + bf16 pack ----------------
// (verbatim R8 — proven across rounds)
__global__ __launch_bounds__(256) void gat_prep(
    const float* __restrict__ x, const float* __restrict__ W_,
    const float* __restrict__ b, const float* __restrict__ a,
    float* __restrict__ s1g, float* __restrict__ s2g,
    float* __restrict__ blockmax, bf16x8* __restrict__ xf) {
  __shared__ float w1s[D], w2s[D], cs[2];
  __shared__ float s1loc[PB];

  const int t = threadIdx.x;
  const int bid = blockIdx.x;

  if (t < 128) {
    const int sel = t >> 6, d = t & 63;
    const float* av = a + sel * D;
    float acc = 0.f;
#pragma unroll
    for (int k = 0; k < D; ++k) acc += W_[k * D + d] * av[k];
    (sel ? w2s : w1s)[d] = acc * LOG2E;
  }
  if (t == 128 || t == 129) {
    const int sel = t - 128;
    float acc = 0.f;
    for (int d = 0; d < D; ++d) acc += b[d] * a[sel * D + d];
    cs[sel] = acc * LOG2E;
  }
  __syncthreads();

  {
    const int r = t >> 3, seg = t & 7;
    const int gi = bid * PB + r;
    const float4 xa = *(const float4*)(x + (size_t)gi * D + seg * 8);
    const float4 xb = *(const float4*)(x + (size_t)gi * D + seg * 8 + 4);
    float p1 = xa.x * w1s[seg * 8 + 0] + xa.y * w1s[seg * 8 + 1] +
               xa.z * w1s[seg * 8 + 2] + xa.w * w1s[seg * 8 + 3] +
               xb.x * w1s[seg * 8 + 4] + xb.y * w1s[seg * 8 + 5] +
               xb.z * w1s[seg * 8 + 6] + xb.w * w1s[seg * 8 + 7];
    float p2 = xa.x * w2s[seg * 8 + 0] + xa.y * w2s[seg * 8 + 1] +
               xa.z * w2s[seg * 8 + 2] + xa.w * w2s[seg * 8 + 3] +
               xb.x * w2s[seg * 8 + 4] + xb.y * w2s[seg * 8 + 5] +
               xb.z * w2s[seg * 8 + 6] + xb.w * w2s[seg * 8 + 7];
#pragma unroll
    for (int off = 4; off; off >>= 1) {
      p1 += __shfl_xor(p1, off, 64);
      p2 += __shfl_xor(p2, off, 64);
    }
    if (seg == 0) {
      const float v1 = p1 + cs[0], v2 = p2 + cs[1];
      s1g[gi] = v1;
      s2g[gi] = v2;
      s1loc[r] = v1;
    }
  }

  {
    const int dt = t >> 6, fl = t & 63;
    const int jb = bid * PB + ((fl >> 4) << 3);
    const int col = dt * 16 + (fl & 15);
    bf16x8 f;
#pragma unroll
    for (int q = 0; q < 8; ++q) f[q] = (__bf16)x[(size_t)(jb + q) * D + col];
    xf[(bid << 8) | (dt << 6) | fl] = f;
  }
  __syncthreads();
  if (t == 0) {
    float m = s1loc[0];
#pragma unroll
    for (int r = 1; r < PB; ++r) m = fmaxf(m, s1loc[r]);
    blockmax[bid] = m;
  }
}

// ---------------- K2: MFMA flash aggregation, split-j partials ----------------
// 256 blocks = 128 i-tiles x 2 j-halves; 512 threads (8 waves, 2/SIMD).
// Each block reads only its half of xf (512 KB): total 128 MB (was 256).
// Per wave per window: 4 A-frags x (4 B + ones) = 20 MFMA; 2-deep prefetch.
__global__ __launch_bounds__(512, 2) void gat_main(
    const bf16x8* __restrict__ xf, const float* __restrict__ s1g,
    const float* __restrict__ s2g, const float* __restrict__ blockmax,
    float* __restrict__ pOut, float* __restrict__ pZ) {
  __shared__ float s1s[NWIN_H * 32];   // 16 KB: this half's s1
  __shared__ float accT[NW][32][65];   // 66.6 KB, two row-passes
  __shared__ float zt[NW][RB];
  __shared__ float gms;

  const int t = threadIdx.x;
  const int lane = t & 63;
  const int w = t >> 6;
  const int arow = lane & 15;
  const int grp = lane >> 4;
  const int bid = blockIdx.x;
  const int itile = bid >> 1, half = bid & 1;
  const int ibase = itile * RB;
  const int jw0 = half * NWIN_H;

  // stage this half's s1 (4096 floats, coalesced float4)
#pragma unroll
  for (int k = 0; k < 2; ++k)
    ((float4*)s1s)[k * 512 + t] = ((const float4*)(s1g + jw0 * 32))[k * 512 + t];

  // global max(s1) from blockmax[256]
  if (t < 64) {
    float v = fmaxf(fmaxf(blockmax[lane], blockmax[lane + 64]),
                    fmaxf(blockmax[lane + 128], blockmax[lane + 192]));
#pragma unroll
    for (int off = 32; off; off >>= 1) v = fmaxf(v, __shfl_xor(v, off, 64));
    if (lane == 0) gms = v;
  }
  __syncthreads();
  const float gm = gms;

  // folded per-row-group constants: p = 2^max(s + Ag, fma(slope, s, Bg))
  float A0v, A1v, A2v, A3v, B0v, B1v, B2v, B3v;
  {
    const float s0 = s2g[ibase + 0 * 16 + arow];
    const float s1v = s2g[ibase + 1 * 16 + arow];
    const float s2v = s2g[ibase + 2 * 16 + arow];
    const float s3v = s2g[ibase + 3 * 16 + arow];
    const float t0 = s0 + gm, t1 = s1v + gm, t2 = s2v + gm, t3 = s3v + gm;
    const float m0 = -fmaxf(t0, NEG_SLOPE * t0);
    const float m1 = -fmaxf(t1, NEG_SLOPE * t1);
    const float m2 = -fmaxf(t2, NEG_SLOPE * t2);
    const float m3 = -fmaxf(t3, NEG_SLOPE * t3);
    A0v = s0 + m0;  B0v = fmaf(NEG_SLOPE, s0, m0);
    A1v = s1v + m1; B1v = fmaf(NEG_SLOPE, s1v, m1);
    A2v = s2v + m2; B2v = fmaf(NEG_SLOPE, s2v, m2);
    A3v = s3v + m3; B3v = fmaf(NEG_SLOPE, s3v, m3);
  }

  f32x4 a00 = {0.f, 0.f, 0.f, 0.f}, a01 = a00, a02 = a00, a03 = a00;
  f32x4 a10 = a00, a11 = a00, a12 = a00, a13 = a00;
  f32x4 a20 = a00, a21 = a00, a22 = a00, a23 = a00;
  f32x4 a30 = a00, a31 = a00, a32 = a00, a33 = a00;
  f32x4 az0 = a00, az1 = a00, az2 = a00, az3 = a00;
  bf16x8 ones;
#pragma unroll
  for (int q = 0; q < 8; ++q) ones[q] = (__bf16)1.0f;

  // 2-deep prefetch: bufA = windows j=0,2,4,..., bufB = j=1,3,5,...
  bf16x8 bA0, bA1, bA2, bA3, bB0, bB1, bB2, bB3;
  {
    const int fa = (jw0 + w) << 8;
    bA0 = xf[fa + 0 * 64 + lane]; bA1 = xf[fa + 1 * 64 + lane];
    bA2 = xf[fa + 2 * 64 + lane]; bA3 = xf[fa + 3 * 64 + lane];
    const int fb = (jw0 + w + 8) << 8;
    bB0 = xf[fb + 0 * 64 + lane]; bB1 = xf[fb + 1 * 64 + lane];
    bB2 = xf[fb + 2 * 64 + lane]; bB3 = xf[fb + 3 * 64 + lane];
  }

  auto process = [&](const bf16x8& x0, const bf16x8& x1, const bf16x8& x2,
                     const bf16x8& x3, int lw) {
    const float4 sa = *(const float4*)&s1s[lw * 32 + grp * 8];
    const float4 sb = *(const float4*)&s1s[lw * 32 + grp * 8 + 4];
    bf16x8 pa0, pa1, pa2, pa3;
    const float* sv = &sa.x;
#pragma unroll
    for (int q = 0; q < 4; ++q) {
      const float s = sv[q];
      pa0[q] = (__bf16)EXP2(fmaxf(s + A0v, fmaf(NEG_SLOPE, s, B0v)));
      pa1[q] = (__bf16)EXP2(fmaxf(s + A1v, fmaf(NEG_SLOPE, s, B1v)));
      pa2[q] = (__bf16)EXP2(fmaxf(s + A2v, fmaf(NEG_SLOPE, s, B2v)));
      pa3[q] = (__bf16)EXP2(fmaxf(s + A3v, fmaf(NEG_SLOPE, s, B3v)));
    }
    const float* sw = &sb.x;
#pragma unroll
    for (int q = 0; q < 4; ++q) {
      const float s = sw[q];
      pa0[4 + q] = (__bf16)EXP2(fmaxf(s + A0v, fmaf(NEG_SLOPE, s, B0v)));
      pa1[4 + q] = (__bf16)EXP2(fmaxf(s + A1v, fmaf(NEG_SLOPE, s, B1v)));
      pa2[4 + q] = (__bf16)EXP2(fmaxf(s + A2v, fmaf(NEG_SLOPE, s, B2v)));
      pa3[4 + q] = (__bf16)EXP2(fmaxf(s + A3v, fmaf(NEG_SLOPE, s, B3v)));
    }
    a00 = __builtin_amdgcn_mfma_f32_16x16x32_bf16(pa0, x0, a00, 0, 0, 0);
    a01 = __builtin_amdgcn_mfma_f32_16x16x32_bf16(pa0, x1, a01, 0, 0, 0);
    a02 = __builtin_amdgcn_mfma_f32_16x16x32_bf16(pa0, x2, a02, 0, 0, 0);
    a03 = __builtin_amdgcn_mfma_f32_16x16x32_bf16(pa0, x3, a03, 0, 0, 0);
    az0 = __builtin_amdgcn_mfma_f32_16x16x32_bf16(pa0, ones, az0, 0, 0, 0);
    a10 = __builtin_amdgcn_mfma_f32_16x16x32_bf16(pa1, x0, a10, 0, 0, 0);
    a11 = __builtin_amdgcn_mfma_f32_16x16x32_bf16(pa1, x1, a11, 0, 0, 0);
    a12 = __builtin_amdgcn_mfma_f32_16x16x32_bf16(pa1, x2, a12, 0, 0, 0);
    a13 = __builtin_amdgcn_mfma_f32_16x16x32_bf16(pa1, x3, a13, 0, 0, 0);
    az1 = __builtin_amdgcn_mfma_f32_16x16x32_bf16(pa1, ones, az1, 0, 0, 0);
    a20 = __builtin_amdgcn_mfma_f32_16x16x32_bf16(pa2, x0, a20, 0, 0, 0);
    a21 = __builtin_amdgcn_mfma_f32_16x16x32_bf16(pa2, x1, a21, 0, 0, 0);
    a22 = __builtin_amdgcn_mfma_f32_16x16x32_bf16(pa2, x2, a22, 0, 0, 0);
    a23 = __builtin_amdgcn_mfma_f32_16x16x32_bf16(pa2, x3, a23, 0, 0, 0);
    az2 = __builtin_amdgcn_mfma_f32_16x16x32_bf16(pa2, ones, az2, 0, 0, 0);
    a30 = __builtin_amdgcn_mfma_f32_16x16x32_bf16(pa3, x0, a30, 0, 0, 0);
    a31 = __builtin_amdgcn_mfma_f32_16x16x32_bf16(pa3, x1, a31, 0, 0, 0);
    a32 = __builtin_amdgcn_mfma_f32_16x16x32_bf16(pa3, x2, a32, 0, 0, 0);
    a33 = __builtin_amdgcn_mfma_f32_16x16x32_bf16(pa3, x3, a33, 0, 0, 0);
    az3 = __builtin_amdgcn_mfma_f32_16x16x32_bf16(pa3, ones, az3, 0, 0, 0);
  };

  // 16 windows per wave (lw = w + 8*j, j=0..15), alternating A/B buffers
  for (int it = 0; it < 8; ++it) {
    const int lwA = w + 16 * it;
    process(bA0, bA1, bA2, bA3, lwA);
    {
      const int lwn = (it == 7) ? lwA : lwA + 16;
      const int f = (jw0 + lwn) << 8;
      bA0 = xf[f + 0 * 64 + lane]; bA1 = xf[f + 1 * 64 + lane];
      bA2 = xf[f + 2 * 64 + lane]; bA3 = xf[f + 3 * 64 + lane];
    }
    const int lwB = w + 16 * it + 8;
    process(bB0, bB1, bB2, bB3, lwB);
    {
      const int lwn = (it == 7) ? lwB : lwB + 16;
      const int f = (jw0 + lwn) << 8;
      bB0 = xf[f + 0 * 64 + lane]; bB1 = xf[f + 1 * 64 + lane];
      bB2 = xf[f + 2 * 64 + lane]; bB3 = xf[f + 3 * 64 + lane];
    }
  }

  // ---- epilogue: Z rows, then two accT passes over row-halves ----
  if (arow == 0) {
#pragma unroll
    for (int reg = 0; reg < 4; ++reg) {
      zt[w][0 * 16 + grp * 4 + reg] = az0[reg];
      zt[w][1 * 16 + grp * 4 + reg] = az1[reg];
      zt[w][2 * 16 + grp * 4 + reg] = az2[reg];
      zt[w][3 * 16 + grp * 4 + reg] = az3[reg];
    }
  }

#pragma unroll
  for (int h = 0; h < 2; ++h) {
    if (h) __syncthreads();  // protect accT reuse
#pragma unroll
    for (int reg = 0; reg < 4; ++reg) {
      if (h == 0) {
        accT[w][0 * 16 + grp * 4 + reg][0 * 16 + arow] = a00[reg];
        accT[w][0 * 16 + grp * 4 + reg][1 * 16 + arow] = a01[reg];
        accT[w][0 * 16 + grp * 4 + reg][2 * 16 + arow] = a02[reg];
        accT[w][0 * 16 + grp * 4 + reg][3 * 16 + arow] = a03[reg];
        accT[w][1 * 16 + grp * 4 + reg][0 * 16 + arow] = a10[reg];
        accT[w][1 * 16 + grp * 4 + reg][1 * 16 + arow] = a11[reg];
        accT[w][1 * 16 + grp * 4 + reg][2 * 16 + arow] = a12[reg];
        accT[w][1 * 16 + grp * 4 + reg][3 * 16 + arow] = a13[reg];
      } else {
        accT[w][0 * 16 + grp * 4 + reg][0 * 16 + arow] = a20[reg];
        accT[w][0 * 16 + grp * 4 + reg][1 * 16 + arow] = a21[reg];
        accT[w][0 * 16 + grp * 4 + reg][2 * 16 + arow] = a22[reg];
        accT[w][0 * 16 + grp * 4 + reg][3 * 16 + arow] = a23[reg];
        accT[w][1 * 16 + grp * 4 + reg][0 * 16 + arow] = a30[reg];
        accT[w][1 * 16 + grp * 4 + reg][1 * 16 + arow] = a31[reg];
        accT[w][1 * 16 + grp * 4 + reg][2 * 16 + arow] = a32[reg];
        accT[w][1 * 16 + grp * 4 + reg][3 * 16 + arow] = a33[reg];
      }
    }
    __syncthreads();
#pragma unroll
    for (int k = 0; k < 4; ++k) {
      const int rloc = w * 4 + k;  // 0..31 within this pass
      float s = 0.f;
#pragma unroll
      for (int v = 0; v < NW; ++v) s += accT[v][rloc][lane];
      const int grow = ibase + h * 32 + rloc;
      pOut[((size_t)half * N + grow) * D + lane] = s;
    }
  }

  if (t < RB) {
    float z = 0.f;
#pragma unroll
    for (int v = 0; v < NW; ++v) z += zt[v][t];
    pZ[half * N + ibase + t] = z;
  }
}

// ---------------- K3: combine partials: out = (p0+p1)/(z0+z1) ----------------
__global__ __launch_bounds__(256) void gat_comb(
    const float* __restrict__ pOut, const float* __restrict__ pZ,
    float* __restrict__ out) {
  const int t = threadIdx.x;
  const int base = blockIdx.x * 512 + t;  // float4 units
#pragma unroll
  for (int k = 0; k < 2; ++k) {
    const int f4 = base + k * 256;
    const int row = f4 >> 4;
    const float inv = 1.0f / (pZ[row] + pZ[N + row]);
    const float4 p0 = ((const float4*)pOut)[f4];
    const float4 p1 = ((const float4*)pOut)[(N * D / 4) + f4];
    float4 o;
    o.x = (p0.x + p1.x) * inv;
    o.y = (p0.y + p1.y) * inv;
    o.z = (p0.z + p1.z) * inv;
    o.w = (p0.w + p1.w) * inv;
    ((float4*)out)[f4] = o;
  }
}

extern "C" void kernel_launch(void* const* d_in, const int* in_sizes, int n_in,
                              void* d_out, int out_size, void* d_ws, size_t ws_size,
                              hipStream_t stream) {
  const float* x = (const float*)d_in[0];   // 8192*64 f32
  const float* W = (const float*)d_in[1];   // 64*64
  const float* b = (const float*)d_in[2];   // 64
  const float* a = (const float*)d_in[3];   // 128

  // ws: s1[8192] | s2[8192] | blockmax[256] | @1MB xf (1MB) | @4MB pOut (4MB) | @8MB pZ (64KB)
  float* ws = (float*)d_ws;
  float* s1 = ws;
  float* s2 = s1 + N;
  float* blockmax = s2 + N;
  bf16x8* xf = (bf16x8*)((char*)d_ws + (1u << 20));
  float* pOut = (float*)((char*)d_ws + (4u << 20));
  float* pZ = (float*)((char*)d_ws + (8u << 20));
  float* out = (float*)d_out;

  gat_prep<<<N / PB, 256, 0, stream>>>(x, W, b, a, s1, s2, blockmax, xf);
  gat_main<<<(N / RB) * 2, 512, 0, stream>>>(xf, s1, s2, blockmax, pOut, pZ);
  gat_comb<<<256, 256, 0, stream>>>(pOut, pZ, out);
}